// Round 11
// baseline (658.495 us; speedup 1.0000x reference)
//
#include <hip/hip_runtime.h>

typedef __attribute__((ext_vector_type(4))) float f32x4;
typedef __attribute__((ext_vector_type(8))) short bf16x8;

constexpr int TOK = 8192;   // B*S
constexpr int DD  = 1024;   // D
constexpr int HH  = 2048;   // H
constexpr int NE  = 8;      // experts

// ---- workspace layout (bytes) ----
// 0      topk_idx   int[16384]
// 65536  topk_prob  f32[16384]
// 131072 counts int[8]; 131104 cursor int[8]; 131136 offsets int[9]
// 131264 token_list int[16384]
// 196800 slot       int[16384]
// 524288            x_bf   bf16[8192*1024]      (16.8 MB)  [dead after gateup]
// 524288            y      bf16[16384*1024]     (33.5 MB)  [overlays x_bf/gw_bf]
// 17301504          gw_bf  bf16[8*2048*1024]
// 50855936          uw_bf  bf16[8*2048*1024]
// 84410368          dw_bf  bf16[8*1024*2048]
// 117964800         act    bf16[16384*2048]
// total need: 185,073,664 B

__device__ __forceinline__ unsigned short f2bf(float f) {
    union { float f; unsigned u; } v; v.f = f;
    unsigned r = v.u + 0x7fffu + ((v.u >> 16) & 1u);   // RNE
    return (unsigned short)(r >> 16);
}

__device__ __forceinline__ void gl2lds16(const void* g, void* l) {
    __builtin_amdgcn_global_load_lds(
        (const __attribute__((address_space(1))) unsigned int*)g,
        (__attribute__((address_space(3))) unsigned int*)l, 16, 0, 0);
}

// ------------- router -------------
__global__ __launch_bounds__(256) void k_router(
    const float* __restrict__ x, const float* __restrict__ rw,
    int* __restrict__ topk_idx, float* __restrict__ topk_prob,
    int* __restrict__ counts, unsigned short* __restrict__ x_bf)
{
    int wave = threadIdx.x >> 6;
    int lane = threadIdx.x & 63;
    int t = blockIdx.x * 4 + wave;

    const float4* xr = (const float4*)(x + (size_t)t * DD);
    float4 xv[4];
#pragma unroll
    for (int i = 0; i < 4; i++) xv[i] = xr[lane + 64 * i];

#pragma unroll
    for (int i = 0; i < 4; i++) {
        ushort4 u4 = make_ushort4(f2bf(xv[i].x), f2bf(xv[i].y),
                                  f2bf(xv[i].z), f2bf(xv[i].w));
        *(ushort4*)(x_bf + (size_t)t * DD + (lane + 64 * i) * 4) = u4;
    }

    float acc[NE];
#pragma unroll
    for (int e = 0; e < NE; e++) {
        const float4* wr = (const float4*)(rw + (size_t)e * DD);
        float s = 0.f;
#pragma unroll
        for (int i = 0; i < 4; i++) {
            float4 w = wr[lane + 64 * i];
            s += xv[i].x * w.x + xv[i].y * w.y + xv[i].z * w.z + xv[i].w * w.w;
        }
        acc[e] = s;
    }
#pragma unroll
    for (int e = 0; e < NE; e++) {
        float s = acc[e];
        for (int m = 32; m >= 1; m >>= 1) s += __shfl_xor(s, m);
        acc[e] = s;
    }
    if (lane == 0) {
        int b0 = 0; float l0 = acc[0];
#pragma unroll
        for (int e = 1; e < NE; e++) if (acc[e] > l0) { l0 = acc[e]; b0 = e; }
        int b1 = -1; float l1 = -3.0e38f;
#pragma unroll
        for (int e = 0; e < NE; e++) if (e != b0 && acc[e] > l1) { l1 = acc[e]; b1 = e; }
        float p0 = 1.f / (1.f + __expf(l1 - l0));
        float p1 = 1.f - p0;
        topk_idx[t * 2 + 0] = b0;  topk_idx[t * 2 + 1] = b1;
        topk_prob[t * 2 + 0] = p0; topk_prob[t * 2 + 1] = p1;
        atomicAdd(&counts[b0], 1);
        atomicAdd(&counts[b1], 1);
    }
}

__global__ void k_scan(const int* __restrict__ counts, int* __restrict__ offsets) {
    if (threadIdx.x == 0) {
        int s = 0;
        for (int e = 0; e < NE; e++) { offsets[e] = s; s += counts[e]; }
        offsets[NE] = s;
    }
}

__global__ __launch_bounds__(256) void k_scatter(
    const int* __restrict__ topk_idx,
    const int* __restrict__ offsets, int* __restrict__ cursor,
    int* __restrict__ token_list, int* __restrict__ slot)
{
    int t = blockIdx.x * 256 + threadIdx.x;
#pragma unroll
    for (int k = 0; k < 2; k++) {
        int e = topk_idx[t * 2 + k];
        int pos = atomicAdd(&cursor[e], 1);
        token_list[offsets[e] + pos] = t;
        slot[t * 2 + k] = offsets[e] + pos;
    }
}

// ---------------- merged f32 -> bf16 weight convert ----------------
__global__ __launch_bounds__(256) void k_cvt_all(
    const float* __restrict__ gw, const float* __restrict__ uw,
    const float* __restrict__ dw,
    unsigned short* __restrict__ gwb, unsigned short* __restrict__ uwb,
    unsigned short* __restrict__ dwb)
{
    constexpr int SEG = NE * HH * DD / 8;
    int i = blockIdx.x * blockDim.x + threadIdx.x;
    int stride = gridDim.x * blockDim.x;
    for (; i < 3 * SEG; i += stride) {
        const float* in; unsigned short* out; int j = i;
        if (j < SEG)            { in = gw; out = gwb; }
        else if (j < 2 * SEG)   { in = uw; out = uwb; j -= SEG; }
        else                    { in = dw; out = dwb; j -= 2 * SEG; }
        const float4* p = (const float4*)(in + (size_t)j * 8);
        float4 a = p[0], b = p[1];
        uint4 v;
        v.x = (unsigned)f2bf(a.x) | ((unsigned)f2bf(a.y) << 16);
        v.y = (unsigned)f2bf(a.z) | ((unsigned)f2bf(a.w) << 16);
        v.z = (unsigned)f2bf(b.x) | ((unsigned)f2bf(b.y) << 16);
        v.w = (unsigned)f2bf(b.z) | ((unsigned)f2bf(b.w) << 16);
        *(uint4*)(out + (size_t)j * 8) = v;
    }
}

// ==================== 256x256 8-phase GEMM machinery (m201 port) ====================
// 8 waves (wm=wid>>2 in {0,1}, wn=wid&3 in 0..3); wave output 128x64.
// LDS: 2 bufs x 64 KB {A 256x64 bf16 at +0, B 256x64 at +32768}.
// K-tile = 4 phases, quadrant order (0,0),(0,1),(1,1),(1,0); bf0/bf1 reg-held.
// Stages of tile t+2 overwrite retired slots of the buffer being consumed.
// vmcnt(8) only at phases 4/8 (4 half-tile stages = 8 loads/thread in flight).

#define FRAG8(base, row, kk) \
    (*(const bf16x8*)((base) + (row) * 128 + (((kk) * 64 + hi16) ^ (((row) & 7) << 4))))

#define DSREADA(Ab, mq) do { _Pragma("unroll") for (int q_ = 0; q_ < 4; q_++) \
    _Pragma("unroll") for (int k_ = 0; k_ < 2; k_++) \
        af[q_][k_] = FRAG8(Ab, wm * 128 + (mq) * 64 + q_ * 16 + l15, k_); } while (0)

#define DSREADB(Bb, nq, BF) do { _Pragma("unroll") for (int j_ = 0; j_ < 2; j_++) \
    _Pragma("unroll") for (int k_ = 0; k_ < 2; k_++) \
        BF[j_][k_] = FRAG8(Bb, wn * 64 + (nq) * 32 + j_ * 16 + l15, k_); } while (0)

#define MFMA16(mq, nq, BF) do { _Pragma("unroll") for (int q_ = 0; q_ < 4; q_++) \
    _Pragma("unroll") for (int j_ = 0; j_ < 2; j_++) \
    _Pragma("unroll") for (int k_ = 0; k_ < 2; k_++) \
        acc[(mq) * 4 + q_][(nq) * 2 + j_] = __builtin_amdgcn_mfma_f32_16x16x32_bf16( \
            af[q_][k_], BF[j_][k_], acc[(mq) * 4 + q_][(nq) * 2 + j_], 0, 0, 0); } while (0)

#define STAGEA(b, ha, T) do { \
    gl2lds16(srcA[ha][0] + (T) * 128, lds + (b) * 65536 + ldsA[ha][0]); \
    gl2lds16(srcA[ha][1] + (T) * 128, lds + (b) * 65536 + ldsA[ha][1]); } while (0)
#define STAGEB(b, hb, T) do { \
    gl2lds16(srcB[hb][0] + (T) * 128, lds + (b) * 65536 + ldsB[hb][0]); \
    gl2lds16(srcB[hb][1] + (T) * 128, lds + (b) * 65536 + ldsB[hb][1]); } while (0)

#define BARF() do { __builtin_amdgcn_s_barrier(); asm volatile("" ::: "memory"); } while (0)
#define VMW(N) asm volatile("s_waitcnt vmcnt(" #N ")" ::: "memory")

// 4 phases of one K-tile in buffer b. STG: stage tile TT into buf b. LASTW at ph4.
#define TILE4(b, Ab, Bb, TT, STG, LASTW) do {                                      \
    DSREADB(Bb, 0, bf0); DSREADA(Ab, 0); BARF();                                   \
    __builtin_amdgcn_s_setprio(1); MFMA16(0, 0, bf0);                              \
    __builtin_amdgcn_s_setprio(0); BARF();                                         \
    DSREADB(Bb, 1, bf1); if (STG) { STAGEA(b, 0, TT); STAGEB(b, 0, TT); } BARF();  \
    __builtin_amdgcn_s_setprio(1); MFMA16(0, 1, bf1);                              \
    __builtin_amdgcn_s_setprio(0); BARF();                                         \
    DSREADA(Ab, 1); if (STG) STAGEB(b, 1, TT); BARF();                             \
    __builtin_amdgcn_s_setprio(1); MFMA16(1, 1, bf1);                              \
    __builtin_amdgcn_s_setprio(0); BARF();                                         \
    if (STG) STAGEA(b, 1, TT); BARF();                                             \
    __builtin_amdgcn_s_setprio(1); MFMA16(1, 0, bf0);                              \
    __builtin_amdgcn_s_setprio(0); LASTW; BARF();                                  \
} while (0)

// gateup: A = 256 gathered token rows; B = 256 rows: per 64-group g (=wn):
// rows [g*64, g*64+32) = gate cols n0g+g*32+[0,32), [+32,+64) = up same cols.
__global__ __launch_bounds__(512) void k_gateup_v8(
    const unsigned short* __restrict__ xb,
    const unsigned short* __restrict__ gwb,
    const unsigned short* __restrict__ uwb,
    const int* __restrict__ offsets,
    const int* __restrict__ token_list,
    unsigned short* __restrict__ act)
{
    extern __shared__ char lds[];   // 131072

    const int bid = blockIdx.x;
    const int e   = bid & 7;            // expert -> XCD
    const int r   = bid >> 3;
    const int m   = r >> 4;             // n-inner: 16 n-slices of one m-tile adjacent
    const int n   = r & 15;
    const int off = offsets[e];
    const int n_e = offsets[e + 1] - off;
    const int m0  = m * 256;
    if (m0 >= n_e) return;
    const int n0g = n * 128;

    const int lane = threadIdx.x & 63, wid = threadIdx.x >> 6;
    const int wm = wid >> 2, wn = wid & 3;
    const int l8 = lane >> 3, l15 = lane & 15, hi16 = (lane >> 4) * 16;
    const int colb = ((lane & 7) * 16) ^ (l8 << 4);

    // stage sources: wave wid handles chunks 2*wid, 2*wid+1 of each half-tile
    const char* srcA[2][2]; unsigned ldsA[2][2];
    const char* srcB[2][2]; unsigned ldsB[2][2];
#pragma unroll
    for (int ha = 0; ha < 2; ha++)
#pragma unroll
        for (int i = 0; i < 2; i++) {
            int c = 2 * wid + i, gA = c >> 3, cc = c & 7;
            int trow = gA * 128 + ha * 64 + cc * 8 + l8;
            int rg = m0 + trow; if (rg > n_e - 1) rg = n_e - 1;
            int tok = token_list[off + rg];
            srcA[ha][i] = (const char*)xb + (size_t)tok * (DD * 2) + colb;
            ldsA[ha][i] = (unsigned)((gA * 128 + ha * 64 + cc * 8) * 128);
        }
#pragma unroll
    for (int hb = 0; hb < 2; hb++)
#pragma unroll
        for (int i = 0; i < 2; i++) {
            int c = 2 * wid + i, gB = c >> 2, cc = c & 3;
            const unsigned short* W = hb ? uwb : gwb;
            srcB[hb][i] = (const char*)W +
                ((size_t)e * HH + n0g + gB * 32 + cc * 8 + l8) * (DD * 2) + colb;
            ldsB[hb][i] = (unsigned)(32768 + (gB * 64 + hb * 32 + cc * 8) * 128);
        }

    const char* A0 = (const char*)lds;
    const char* B0 = A0 + 32768;
    const char* A1 = A0 + 65536;
    const char* B1 = A1 + 32768;

    f32x4 acc[8][4] = {};
    bf16x8 af[4][2], bf0[2][2], bf1[2][2];

    // prologue: tiles 0 (buf0) and 1 (buf1); oldest 8 loads = tile 0
    STAGEA(0, 0, 0); STAGEB(0, 0, 0); STAGEB(0, 1, 0); STAGEA(0, 1, 0);
    STAGEA(1, 0, 1); STAGEB(1, 0, 1); STAGEB(1, 1, 1); STAGEA(1, 1, 1);
    VMW(8); BARF();

    constexpr int NITER = (DD * 2 / 128) / 2;   // 8
    for (int i = 0; i < NITER - 1; ++i) {
        TILE4(0, A0, B0, 2 * i + 2, 1, VMW(8));
        TILE4(1, A1, B1, 2 * i + 3, 1, VMW(8));
    }
    TILE4(0, A0, B0, 0, 0, VMW(0));
    TILE4(1, A1, B1, 0, 0, );

    // epilogue: silu(g)*u -> act bf16 (nj 0,1 = gate, 2,3 = up)
#pragma unroll
    for (int mi = 0; mi < 8; mi++) {
#pragma unroll
        for (int r2 = 0; r2 < 4; r2++) {
            int row = wm * 128 + mi * 16 + (lane >> 4) * 4 + r2;
            int rg = m0 + row;
            if (rg >= n_e) continue;
            size_t rowbase = (size_t)(off + rg) * HH + n0g + wn * 32;
#pragma unroll
            for (int jj = 0; jj < 2; jj++) {
                float gg = acc[mi][jj][r2];
                float uu = acc[mi][2 + jj][r2];
                float sv = gg / (1.f + __expf(-gg)) * uu;
                act[rowbase + jj * 16 + l15] = f2bf(sv);
            }
        }
    }
}

// down: A = 256 grouped act rows; B = 256 D-cols of dw; K = 2048 -> y bf16
__global__ __launch_bounds__(512) void k_down_v8(
    const unsigned short* __restrict__ act,
    const unsigned short* __restrict__ dwb,
    const int* __restrict__ offsets,
    unsigned short* __restrict__ y)
{
    extern __shared__ char lds[];   // 131072

    const int bid = blockIdx.x;
    const int e   = bid & 7;
    const int r   = bid >> 3;
    const int m   = r >> 2;
    const int n   = r & 3;
    const int off = offsets[e];
    const int n_e = offsets[e + 1] - off;
    const int m0  = m * 256;
    if (m0 >= n_e) return;
    const int n0  = n * 256;

    const int lane = threadIdx.x & 63, wid = threadIdx.x >> 6;
    const int wm = wid >> 2, wn = wid & 3;
    const int l8 = lane >> 3, l15 = lane & 15, hi16 = (lane >> 4) * 16;
    const int colb = ((lane & 7) * 16) ^ (l8 << 4);

    const char* srcA[2][2]; unsigned ldsA[2][2];
    const char* srcB[2][2]; unsigned ldsB[2][2];
#pragma unroll
    for (int ha = 0; ha < 2; ha++)
#pragma unroll
        for (int i = 0; i < 2; i++) {
            int c = 2 * wid + i, gA = c >> 3, cc = c & 7;
            int trow = gA * 128 + ha * 64 + cc * 8 + l8;
            int rg = m0 + trow; if (rg > n_e - 1) rg = n_e - 1;
            srcA[ha][i] = (const char*)act + (size_t)(off + rg) * (HH * 2) + colb;
            ldsA[ha][i] = (unsigned)((gA * 128 + ha * 64 + cc * 8) * 128);
        }
#pragma unroll
    for (int hb = 0; hb < 2; hb++)
#pragma unroll
        for (int i = 0; i < 2; i++) {
            int c = 2 * wid + i, gB = c >> 2, cc = c & 3;
            int R = gB * 64 + hb * 32 + cc * 8 + l8;
            srcB[hb][i] = (const char*)dwb +
                ((size_t)e * DD + n0 + R) * (HH * 2) + colb;
            ldsB[hb][i] = (unsigned)(32768 + (gB * 64 + hb * 32 + cc * 8) * 128);
        }

    const char* A0 = (const char*)lds;
    const char* B0 = A0 + 32768;
    const char* A1 = A0 + 65536;
    const char* B1 = A1 + 32768;

    f32x4 acc[8][4] = {};
    bf16x8 af[4][2], bf0[2][2], bf1[2][2];

    STAGEA(0, 0, 0); STAGEB(0, 0, 0); STAGEB(0, 1, 0); STAGEA(0, 1, 0);
    STAGEA(1, 0, 1); STAGEB(1, 0, 1); STAGEB(1, 1, 1); STAGEA(1, 1, 1);
    VMW(8); BARF();

    constexpr int NITER = (HH * 2 / 128) / 2;   // 16
    for (int i = 0; i < NITER - 1; ++i) {
        TILE4(0, A0, B0, 2 * i + 2, 1, VMW(8));
        TILE4(1, A1, B1, 2 * i + 3, 1, VMW(8));
    }
    TILE4(0, A0, B0, 0, 0, VMW(0));
    TILE4(1, A1, B1, 0, 0, );

    // epilogue: y[grouped row] = result bf16 (combine applies probs)
#pragma unroll
    for (int mi = 0; mi < 8; mi++) {
#pragma unroll
        for (int r2 = 0; r2 < 4; r2++) {
            int row = wm * 128 + mi * 16 + (lane >> 4) * 4 + r2;
            int rg = m0 + row;
            if (rg >= n_e) continue;
            size_t ybase = (size_t)(off + rg) * DD + n0 + wn * 64;
#pragma unroll
            for (int nj = 0; nj < 4; nj++)
                y[ybase + nj * 16 + l15] = f2bf(acc[mi][nj][r2]);
        }
    }
}

// ---------------- combine: out[t] = p0*y[slot0] + p1*y[slot1] ----------------
__global__ __launch_bounds__(256) void k_combine(
    const unsigned short* __restrict__ y,
    const int* __restrict__ slot,
    const float* __restrict__ topk_prob,
    float* __restrict__ out)
{
    int t = blockIdx.x * 2 + (threadIdx.x >> 7);
    int i = threadIdx.x & 127;
    int s0 = slot[t * 2 + 0], s1 = slot[t * 2 + 1];
    float p0 = topk_prob[t * 2 + 0], p1 = topk_prob[t * 2 + 1];
    bf16x8 a = *(const bf16x8*)(y + (size_t)s0 * DD + i * 8);
    bf16x8 b = *(const bf16x8*)(y + (size_t)s1 * DD + i * 8);
    float o[8];
#pragma unroll
    for (int j = 0; j < 8; j++) {
        union { unsigned u; float f; } va, vb;
        va.u = ((unsigned)(unsigned short)a[j]) << 16;
        vb.u = ((unsigned)(unsigned short)b[j]) << 16;
        o[j] = p0 * va.f + p1 * vb.f;
    }
    float4* op = (float4*)(out + (size_t)t * DD + i * 8);
    op[0] = make_float4(o[0], o[1], o[2], o[3]);
    op[1] = make_float4(o[4], o[5], o[6], o[7]);
}

extern "C" void kernel_launch(void* const* d_in, const int* in_sizes, int n_in,
                              void* d_out, int out_size, void* d_ws, size_t ws_size,
                              hipStream_t stream) {
    const float* x  = (const float*)d_in[0];
    const float* rw = (const float*)d_in[1];
    const float* gw = (const float*)d_in[2];
    const float* uw = (const float*)d_in[3];
    const float* dw = (const float*)d_in[4];
    float* out = (float*)d_out;

    char* ws = (char*)d_ws;
    int*   topk_idx   = (int*)(ws + 0);
    float* topk_prob  = (float*)(ws + 65536);
    int*   counts     = (int*)(ws + 131072);
    int*   cursor     = (int*)(ws + 131104);
    int*   offsets    = (int*)(ws + 131136);
    int*   token_list = (int*)(ws + 131264);
    int*   slot       = (int*)(ws + 196800);

    unsigned short* x_bf  = (unsigned short*)(ws + 524288);
    unsigned short* y     = (unsigned short*)(ws + 524288);  // overlays x_bf/gw_bf (dead)
    unsigned short* gw_bf = (unsigned short*)(ws + 17301504);
    unsigned short* uw_bf = (unsigned short*)(ws + 50855936);
    unsigned short* dw_bf = (unsigned short*)(ws + 84410368);
    unsigned short* act   = (unsigned short*)(ws + 117964800);

    hipMemsetAsync(ws + 131072, 0, 64, stream);   // counts + cursor

    k_router<<<TOK / 4, 256, 0, stream>>>(x, rw, topk_idx, topk_prob, counts, x_bf);
    k_scan<<<1, 64, 0, stream>>>(counts, offsets);
    k_scatter<<<TOK / 256, 256, 0, stream>>>(topk_idx, offsets, cursor,
                                             token_list, slot);

    k_cvt_all<<<2048, 256, 0, stream>>>(gw, uw, dw, gw_bf, uw_bf, dw_bf);

    // gateup: 4096 blocks = e(8, XCD-pinned) x m(32, 256-row) x n(16, 128 H-cols)
    k_gateup_v8<<<4096, 512, 131072, stream>>>(x_bf, gw_bf, uw_bf, offsets,
                                               token_list, act);
    // down: 1024 blocks = e(8) x m(32, 256-row) x n(4, 256 D-cols)
    k_down_v8<<<1024, 512, 131072, stream>>>(act, dw_bf, offsets, y);

    k_combine<<<TOK / 2, 256, 0, stream>>>(y, slot, topk_prob, out);
}